// Round 1
// baseline (161.788 us; speedup 1.0000x reference)
//
#include <hip/hip_runtime.h>
#include <hip/hip_bf16.h>
#include <cstdint>
#include <cstddef>

// ---------------------------------------------------------------------------
// LocalAttention: B=4, S=2048, D=1024, WINDOW=10 (|i-j| <= 5)
//   Q = x@Wq.T + bq ; K = x@Wk.T + bk ; V = x@Wv.T + bv      (bf16 MFMA GEMM)
//   scores band -> softmax -> attn (band only, rest exactly 0) (f32)
//   ctx = attn@V (band)                                        (f32 -> bf16)
//   out = ctx@Wo.T + bo                                        (bf16 MFMA GEMM)
// Outputs concatenated in d_out: out [4,2048,1024] f32, attn [4,2048,2048] f32
// ---------------------------------------------------------------------------

typedef __attribute__((ext_vector_type(8))) short bf16x8;
typedef __attribute__((ext_vector_type(4))) float f32x4;

#define GPTR(x) ((const __attribute__((address_space(1))) void*)(x))
#define LPTR(x) ((__attribute__((address_space(3))) void*)(x))

__device__ __forceinline__ unsigned short f2bf(float f) {
    __hip_bfloat16 h = __float2bfloat16(f);
    unsigned short u;
    __builtin_memcpy(&u, &h, 2);
    return u;
}

// ------------------------------ f32 -> bf16 convert ------------------------
__global__ void cvt_f32_to_bf16(const float* __restrict__ in,
                                unsigned short* __restrict__ out, int n4) {
    int idx = blockIdx.x * blockDim.x + threadIdx.x;
    if (idx >= n4) return;
    f32x4 v = reinterpret_cast<const f32x4*>(in)[idx];
    ushort4 o;
    o.x = f2bf(v[0]); o.y = f2bf(v[1]); o.z = f2bf(v[2]); o.w = f2bf(v[3]);
    reinterpret_cast<ushort4*>(out)[idx] = o;
}

// ------------------------------ bf16 GEMM (C = A @ B^T + bias) -------------
// A: [M,K] bf16 row-major, Bw: [N,K] bf16 row-major (i.e. W for y=x@W.T)
// C: [M,N] f32.  128x128 tile, BK=64, 256 threads = 4 waves (2x2 of 64x64).
// m97 structure: global_load_lds width 16, linear LDS dest, T2 XOR swizzle
// applied via inverse-swizzled global SOURCE + swizzled ds_read (rule #21).
__launch_bounds__(256, 2)
__global__ void gemm_bt_bias(const unsigned short* __restrict__ A,
                             const unsigned short* __restrict__ Bw,
                             const float* __restrict__ bias,
                             float* __restrict__ C,
                             int M, int N, int K) {
    __shared__ unsigned short As[128 * 64];
    __shared__ unsigned short Bs[128 * 64];
    const int tid  = threadIdx.x;
    const int lane = tid & 63;
    const int w    = tid >> 6;
    const int wr   = w >> 1;       // wave row (0..1) -> 64 rows each
    const int wc   = w & 1;        // wave col (0..1) -> 64 cols each
    const int tm   = blockIdx.x;
    const int tn   = blockIdx.y;

    f32x4 acc[4][4];
#pragma unroll
    for (int m = 0; m < 4; ++m)
#pragma unroll
        for (int n = 0; n < 4; ++n)
            acc[m][n] = (f32x4){0.f, 0.f, 0.f, 0.f};

    const int lrow8 = lane >> 3;          // 0..7 (row within 8-row chunk)
    const int lcolb = (lane & 7) << 4;    // byte col 0..112 step 16

    const char* Abase = (const char*)(A + (size_t)tm * 128 * (size_t)K);
    const char* Bbase = (const char*)(Bw + (size_t)tn * 128 * (size_t)K);
    const size_t rstride = (size_t)K * 2; // bytes per row

    const int nk = K >> 6;
    for (int t = 0; t < nk; ++t) {
        const size_t k0b = ((size_t)t << 6) * 2; // byte offset along K
        // stage A-tile and B-tile (each 128 rows x 64 bf16 = 16 KB)
        // chunk c = w*4+ii covers LDS bytes [c*1024, c*1024+1024): rows c*8..c*8+7
#pragma unroll
        for (int ii = 0; ii < 4; ++ii) {
            const int c   = (w << 2) + ii;        // 0..15
            const int row = (c << 3) + lrow8;     // 0..127
            const int csrc = lcolb ^ ((row & 7) << 4); // inverse-swizzled source col
            __builtin_amdgcn_global_load_lds(
                GPTR(Abase + (size_t)row * rstride + k0b + (size_t)csrc),
                LPTR((char*)As + (c << 10)), 16, 0, 0);
            __builtin_amdgcn_global_load_lds(
                GPTR(Bbase + (size_t)row * rstride + k0b + (size_t)csrc),
                LPTR((char*)Bs + (c << 10)), 16, 0, 0);
        }
        __syncthreads();   // drains vmcnt -> tiles complete

#pragma unroll
        for (int kk = 0; kk < 2; ++kk) {
            bf16x8 af[4], bfr[4];
            const int cb = (kk << 6) + ((lane >> 4) << 4); // nominal byte col
#pragma unroll
            for (int m = 0; m < 4; ++m) {
                const int row = (wr << 6) + (m << 4) + (lane & 15);
                af[m] = *reinterpret_cast<const bf16x8*>(
                    (const char*)As + row * 128 + (cb ^ ((row & 7) << 4)));
            }
#pragma unroll
            for (int n = 0; n < 4; ++n) {
                const int row = (wc << 6) + (n << 4) + (lane & 15);
                bfr[n] = *reinterpret_cast<const bf16x8*>(
                    (const char*)Bs + row * 128 + (cb ^ ((row & 7) << 4)));
            }
#pragma unroll
            for (int m = 0; m < 4; ++m)
#pragma unroll
                for (int n = 0; n < 4; ++n)
                    acc[m][n] = __builtin_amdgcn_mfma_f32_16x16x32_bf16(
                        af[m], bfr[n], acc[m][n], 0, 0, 0);
        }
        __syncthreads();   // protect LDS before next stage
    }

    // epilogue: C/D layout col = lane&15, row = (lane>>4)*4 + reg
    const int col0 = (tn << 7) + (wc << 6) + (lane & 15);
    const int row0 = (tm << 7) + (wr << 6) + ((lane >> 4) << 2);
#pragma unroll
    for (int n = 0; n < 4; ++n) {
        const int col = col0 + (n << 4);
        const float bb = bias[col];
#pragma unroll
        for (int m = 0; m < 4; ++m) {
            const int row = row0 + (m << 4);
#pragma unroll
            for (int r = 0; r < 4; ++r)
                C[(size_t)(row + r) * (size_t)N + col] = acc[m][n][r] + bb;
        }
    }
}

// ------------------------------ band attention -----------------------------
// One wave per (b,i) row. Fixed 11-wide window, clamped j, invalid = -1e30.
// All-lane dot reduce via shfl_xor; f32 softmax; attn band -> d_out;
// context (attn@V) -> bf16 workspace.
__launch_bounds__(256, 3)
__global__ void attn_band_kernel(const float* __restrict__ Q,
                                 const float* __restrict__ K,
                                 const float* __restrict__ V,
                                 float* __restrict__ attn,
                                 unsigned short* __restrict__ ctx) {
    const int nb    = gridDim.x;
    const int chunk = nb >> 3;                       // XCD-contiguous swizzle
    const int bid   = blockIdx.x;
    const int rb    = (bid & 7) * chunk + (bid >> 3);
    const int w     = threadIdx.x >> 6;
    const int lane  = threadIdx.x & 63;
    const int g     = (rb << 2) + w;                 // global row 0..8191
    const int b     = g >> 11;
    const int i     = g & 2047;

    const f32x4* Q4 = reinterpret_cast<const f32x4*>(Q) + (size_t)g * 256;
    const f32x4 q0 = Q4[lane], q1 = Q4[64 + lane], q2 = Q4[128 + lane], q3 = Q4[192 + lane];

    float s[11];
#pragma unroll
    for (int jj = 0; jj < 11; ++jj) {
        const int j = i - 5 + jj;
        const bool valid = ((unsigned)j < 2048u);
        const int jc = min(max(j, 0), 2047);
        const f32x4* K4 = reinterpret_cast<const f32x4*>(K) + ((size_t)(b << 11) + jc) * 256;
        const f32x4 k0 = K4[lane], k1 = K4[64 + lane], k2 = K4[128 + lane], k3 = K4[192 + lane];
        float d = 0.f;
#pragma unroll
        for (int t = 0; t < 4; ++t)
            d += q0[t] * k0[t] + q1[t] * k1[t] + q2[t] * k2[t] + q3[t] * k3[t];
#pragma unroll
        for (int off = 32; off >= 1; off >>= 1) d += __shfl_xor(d, off, 64);
        s[jj] = valid ? d * 0.03125f : -1e30f;   // 1/sqrt(1024)
    }

    float mx = s[0];
#pragma unroll
    for (int jj = 1; jj < 11; ++jj) mx = fmaxf(mx, s[jj]);
    float p[11];
    float sum = 0.f;
#pragma unroll
    for (int jj = 0; jj < 11; ++jj) { p[jj] = expf(s[jj] - mx); sum += p[jj]; }
    const float inv = 1.0f / sum;

    // scatter attn band (rest of the row is 0 from memset)
    float myp = 0.f;
#pragma unroll
    for (int jj = 0; jj < 11; ++jj) myp = (lane == jj) ? p[jj] : myp;
    const int myj = i - 5 + lane;
    if (lane < 11 && (unsigned)myj < 2048u)
        attn[(size_t)g * 2048 + myj] = myp * inv;

    // context = sum_j p_j * V[j]
    f32x4 c0 = {0.f,0.f,0.f,0.f}, c1 = {0.f,0.f,0.f,0.f};
    f32x4 c2 = {0.f,0.f,0.f,0.f}, c3 = {0.f,0.f,0.f,0.f};
#pragma unroll
    for (int jj = 0; jj < 11; ++jj) {
        const int j = i - 5 + jj;
        const int jc = min(max(j, 0), 2047);
        const float pj = p[jj] * inv;   // 0 for invalid
        const f32x4* V4 = reinterpret_cast<const f32x4*>(V) + ((size_t)(b << 11) + jc) * 256;
        c0 += V4[lane] * pj;
        c1 += V4[64 + lane] * pj;
        c2 += V4[128 + lane] * pj;
        c3 += V4[192 + lane] * pj;
    }
    unsigned short* cp = ctx + (size_t)g * 1024;
    {
        ushort4 o;
        o.x = f2bf(c0[0]); o.y = f2bf(c0[1]); o.z = f2bf(c0[2]); o.w = f2bf(c0[3]);
        *reinterpret_cast<ushort4*>(cp + (lane << 2)) = o;
        o.x = f2bf(c1[0]); o.y = f2bf(c1[1]); o.z = f2bf(c1[2]); o.w = f2bf(c1[3]);
        *reinterpret_cast<ushort4*>(cp + 256 + (lane << 2)) = o;
        o.x = f2bf(c2[0]); o.y = f2bf(c2[1]); o.z = f2bf(c2[2]); o.w = f2bf(c2[3]);
        *reinterpret_cast<ushort4*>(cp + 512 + (lane << 2)) = o;
        o.x = f2bf(c3[0]); o.y = f2bf(c3[1]); o.z = f2bf(c3[2]); o.w = f2bf(c3[3]);
        *reinterpret_cast<ushort4*>(cp + 768 + (lane << 2)) = o;
    }
}

// ------------------------------ launch --------------------------------------
extern "C" void kernel_launch(void* const* d_in, const int* in_sizes, int n_in,
                              void* d_out, int out_size, void* d_ws, size_t ws_size,
                              hipStream_t stream) {
    const float* x  = (const float*)d_in[0];
    const float* Wq = (const float*)d_in[1];
    const float* bq = (const float*)d_in[2];
    const float* Wk = (const float*)d_in[3];
    const float* bk = (const float*)d_in[4];
    const float* Wv = (const float*)d_in[5];
    const float* bv = (const float*)d_in[6];
    const float* Wo = (const float*)d_in[7];
    const float* bo = (const float*)d_in[8];

    const size_t MS = 8192;   // B*S
    const size_t DD = 1024;

    float* out  = (float*)d_out;            // [8192,1024]
    float* attn = out + MS * DD;            // [4,2048,2048]

    char* ws = (char*)d_ws;
    unsigned short* xh  = (unsigned short*)ws; ws += MS * DD * 2;
    unsigned short* Wqh = (unsigned short*)ws; ws += DD * DD * 2;
    unsigned short* Wkh = (unsigned short*)ws; ws += DD * DD * 2;
    unsigned short* Wvh = (unsigned short*)ws; ws += DD * DD * 2;
    unsigned short* Woh = (unsigned short*)ws; ws += DD * DD * 2;
    float* Qb = (float*)ws;                    ws += MS * DD * 4;
    float* Kb = (float*)ws;                    ws += MS * DD * 4;
    float* Vb = (float*)ws;                    ws += MS * DD * 4;
    unsigned short* ctx = (unsigned short*)ws; ws += MS * DD * 2;

    // zero the attn output region (band values overwritten below; rest stays 0)
    hipMemsetAsync(attn, 0, (size_t)4 * 2048 * 2048 * sizeof(float), stream);

    // bf16 conversions
    cvt_f32_to_bf16<<<dim3(2097152 / 256), dim3(256), 0, stream>>>(x, xh, 2097152);
    cvt_f32_to_bf16<<<dim3(262144 / 256), dim3(256), 0, stream>>>(Wq, Wqh, 262144);
    cvt_f32_to_bf16<<<dim3(262144 / 256), dim3(256), 0, stream>>>(Wk, Wkh, 262144);
    cvt_f32_to_bf16<<<dim3(262144 / 256), dim3(256), 0, stream>>>(Wv, Wvh, 262144);
    cvt_f32_to_bf16<<<dim3(262144 / 256), dim3(256), 0, stream>>>(Wo, Woh, 262144);

    // Q/K/V projections
    dim3 gg(64, 8);
    gemm_bt_bias<<<gg, dim3(256), 0, stream>>>(xh, Wqh, bq, Qb, 8192, 1024, 1024);
    gemm_bt_bias<<<gg, dim3(256), 0, stream>>>(xh, Wkh, bk, Kb, 8192, 1024, 1024);
    gemm_bt_bias<<<gg, dim3(256), 0, stream>>>(xh, Wvh, bv, Vb, 8192, 1024, 1024);

    // band attention (attn -> d_out, ctx -> ws bf16)
    attn_band_kernel<<<dim3(2048), dim3(256), 0, stream>>>(Qb, Kb, Vb, attn, ctx);

    // output projection
    gemm_bt_bias<<<gg, dim3(256), 0, stream>>>(ctx, Woh, bo, out, 8192, 1024, 1024);
}

// Round 2
// 133.115 us; speedup vs baseline: 1.2154x; 1.2154x over previous
//
#include <hip/hip_runtime.h>
#include <hip/hip_bf16.h>
#include <cstdint>
#include <cstddef>

// ---------------------------------------------------------------------------
// LocalAttention: B=4, S=2048, D=1024, WINDOW=10 (|i-j| <= 5)
//   QKV = x @ [Wq;Wk;Wv].T + b   (one fused bf16 MFMA GEMM, bf16 out)
//   band softmax (f32) -> attn full rows written by kernel (no memset)
//   ctx = attn@V (band, f32 acc -> bf16)
//   out = ctx@Wo.T + bo          (bf16 MFMA GEMM, f32 out)
// d_out: out [4,2048,1024] f32, attn [4,2048,2048] f32 (concatenated)
// ---------------------------------------------------------------------------

typedef __attribute__((ext_vector_type(8))) short bf16x8;
typedef __attribute__((ext_vector_type(4))) float f32x4;
typedef __attribute__((ext_vector_type(8))) unsigned short ushortx8;

#define GPTR(x) ((const __attribute__((address_space(1))) void*)(x))
#define LPTR(x) ((__attribute__((address_space(3))) void*)(x))

__device__ __forceinline__ unsigned short f2bf(float f) {
    __hip_bfloat16 h = __float2bfloat16(f);
    unsigned short u;
    __builtin_memcpy(&u, &h, 2);
    return u;
}
__device__ __forceinline__ float bf2f(unsigned short u) {
    unsigned int x = ((unsigned int)u) << 16;
    float f;
    __builtin_memcpy(&f, &x, 4);
    return f;
}

// ------------------- fused f32->bf16 convert: x + Wq/Wk/Wv -> Wcat, Wo -----
// idx counts f32x4 units: [0,2097152) = x ; then 4 segments of 262144 each.
__global__ void cvt_all(const float* __restrict__ x,
                        const float* __restrict__ Wq, const float* __restrict__ Wk,
                        const float* __restrict__ Wv, const float* __restrict__ Wo,
                        unsigned short* __restrict__ xh,
                        unsigned short* __restrict__ Wcat,
                        unsigned short* __restrict__ Woh) {
    const int idx = blockIdx.x * blockDim.x + threadIdx.x;
    const float* src;
    unsigned short* dst;
    int s_off, d_off;
    if (idx < 2097152) {
        src = x; dst = xh; s_off = idx; d_off = idx;
    } else {
        const int r   = idx - 2097152;
        const int seg = r >> 18;          // 0..3
        const int off = r & 262143;
        src   = (seg == 0) ? Wq : (seg == 1) ? Wk : (seg == 2) ? Wv : Wo;
        dst   = (seg < 3) ? Wcat : Woh;
        s_off = off;
        d_off = (seg < 3) ? (seg << 18) + off : off;
    }
    f32x4 v = reinterpret_cast<const f32x4*>(src)[s_off];
    ushort4 o;
    o.x = f2bf(v[0]); o.y = f2bf(v[1]); o.z = f2bf(v[2]); o.w = f2bf(v[3]);
    reinterpret_cast<ushort4*>(dst)[d_off] = o;
}

// ------------------- GEMM core: 128x128 tile, BK=64, 4 waves (m97) ---------
// A [M,K] bf16 rm, Bw [N,K] bf16 rm; acc = A_tile @ Bw_tile^T.
// global_load_lds w16, linear LDS dest, T2 swizzle via inverse-swizzled
// global source + swizzled ds_read (rule #21).
__device__ __forceinline__ void gemm_core(const unsigned short* __restrict__ A,
                                          const unsigned short* __restrict__ Bw,
                                          int K, int tm, int tn,
                                          unsigned short* As, unsigned short* Bs,
                                          f32x4 (&acc)[4][4]) {
    const int tid  = threadIdx.x;
    const int lane = tid & 63;
    const int w    = tid >> 6;
    const int wr   = w >> 1;
    const int wc   = w & 1;

    const int lrow8 = lane >> 3;
    const int lcolb = (lane & 7) << 4;

    const char* Abase = (const char*)(A + (size_t)tm * 128 * (size_t)K);
    const char* Bbase = (const char*)(Bw + (size_t)tn * 128 * (size_t)K);
    const size_t rstride = (size_t)K * 2;

    const int nk = K >> 6;
    for (int t = 0; t < nk; ++t) {
        const size_t k0b = ((size_t)t << 6) * 2;
#pragma unroll
        for (int ii = 0; ii < 4; ++ii) {
            const int c    = (w << 2) + ii;
            const int row  = (c << 3) + lrow8;
            const int csrc = lcolb ^ ((row & 7) << 4);
            __builtin_amdgcn_global_load_lds(
                GPTR(Abase + (size_t)row * rstride + k0b + (size_t)csrc),
                LPTR((char*)As + (c << 10)), 16, 0, 0);
            __builtin_amdgcn_global_load_lds(
                GPTR(Bbase + (size_t)row * rstride + k0b + (size_t)csrc),
                LPTR((char*)Bs + (c << 10)), 16, 0, 0);
        }
        __syncthreads();

#pragma unroll
        for (int kk = 0; kk < 2; ++kk) {
            bf16x8 af[4], bfr[4];
            const int cb = (kk << 6) + ((lane >> 4) << 4);
#pragma unroll
            for (int m = 0; m < 4; ++m) {
                const int row = (wr << 6) + (m << 4) + (lane & 15);
                af[m] = *reinterpret_cast<const bf16x8*>(
                    (const char*)As + row * 128 + (cb ^ ((row & 7) << 4)));
            }
#pragma unroll
            for (int n = 0; n < 4; ++n) {
                const int row = (wc << 6) + (n << 4) + (lane & 15);
                bfr[n] = *reinterpret_cast<const bf16x8*>(
                    (const char*)Bs + row * 128 + (cb ^ ((row & 7) << 4)));
            }
#pragma unroll
            for (int m = 0; m < 4; ++m)
#pragma unroll
                for (int n = 0; n < 4; ++n)
                    acc[m][n] = __builtin_amdgcn_mfma_f32_16x16x32_bf16(
                        af[m], bfr[n], acc[m][n], 0, 0, 0);
        }
        __syncthreads();
    }
}

// fused QKV projection: C bf16 [M, 3072], bias selected by column segment
__launch_bounds__(256, 2)
__global__ void gemm_qkv(const unsigned short* __restrict__ A,
                         const unsigned short* __restrict__ Bw,
                         const float* __restrict__ bq, const float* __restrict__ bk,
                         const float* __restrict__ bv,
                         unsigned short* __restrict__ C, int M, int N, int K) {
    __shared__ unsigned short As[128 * 64];
    __shared__ unsigned short Bs[128 * 64];
    f32x4 acc[4][4];
#pragma unroll
    for (int m = 0; m < 4; ++m)
#pragma unroll
        for (int n = 0; n < 4; ++n) acc[m][n] = (f32x4){0.f, 0.f, 0.f, 0.f};

    gemm_core(A, Bw, K, blockIdx.x, blockIdx.y, As, Bs, acc);

    const int lane = threadIdx.x & 63;
    const int w    = threadIdx.x >> 6;
    const int wr   = w >> 1, wc = w & 1;
    const int seg  = blockIdx.y >> 3;   // 0:Q 1:K 2:V (8 tiles of 128 per 1024)
    const float* bp = (seg == 0) ? bq : (seg == 1) ? bk : bv;

    const int col0 = (blockIdx.y << 7) + (wc << 6) + (lane & 15);
    const int row0 = (blockIdx.x << 7) + (wr << 6) + ((lane >> 4) << 2);
#pragma unroll
    for (int n = 0; n < 4; ++n) {
        const int col = col0 + (n << 4);
        const float bb = bp[col & 1023];
#pragma unroll
        for (int m = 0; m < 4; ++m) {
            const int row = row0 + (m << 4);
#pragma unroll
            for (int r = 0; r < 4; ++r)
                C[(size_t)(row + r) * (size_t)N + col] = f2bf(acc[m][n][r] + bb);
        }
    }
}

// output projection: C f32 [M, 1024]
__launch_bounds__(256, 2)
__global__ void gemm_out(const unsigned short* __restrict__ A,
                         const unsigned short* __restrict__ Bw,
                         const float* __restrict__ bias,
                         float* __restrict__ C, int M, int N, int K) {
    __shared__ unsigned short As[128 * 64];
    __shared__ unsigned short Bs[128 * 64];
    f32x4 acc[4][4];
#pragma unroll
    for (int m = 0; m < 4; ++m)
#pragma unroll
        for (int n = 0; n < 4; ++n) acc[m][n] = (f32x4){0.f, 0.f, 0.f, 0.f};

    gemm_core(A, Bw, K, blockIdx.x, blockIdx.y, As, Bs, acc);

    const int lane = threadIdx.x & 63;
    const int w    = threadIdx.x >> 6;
    const int wr   = w >> 1, wc = w & 1;
    const int col0 = (blockIdx.y << 7) + (wc << 6) + (lane & 15);
    const int row0 = (blockIdx.x << 7) + (wr << 6) + ((lane >> 4) << 2);
#pragma unroll
    for (int n = 0; n < 4; ++n) {
        const int col = col0 + (n << 4);
        const float bb = bias[col];
#pragma unroll
        for (int m = 0; m < 4; ++m) {
            const int row = row0 + (m << 4);
#pragma unroll
            for (int r = 0; r < 4; ++r)
                C[(size_t)(row + r) * (size_t)N + col] = acc[m][n][r] + bb;
        }
    }
}

// ------------------- band attention, writes FULL attn rows ------------------
// QKV [8192, 3072] bf16 (Q | K | V per row). One wave per (b,i) row.
__launch_bounds__(256, 4)
__global__ void attn_band_kernel(const unsigned short* __restrict__ QKV,
                                 float* __restrict__ attn,
                                 unsigned short* __restrict__ ctx) {
    __shared__ float psm[4][16];
    const int bid  = blockIdx.x;
    const int rb   = (bid & 7) * 256 + (bid >> 3);   // XCD-contiguous swizzle
    const int w    = threadIdx.x >> 6;
    const int lane = threadIdx.x & 63;
    const int g    = (rb << 2) + w;                  // row 0..8191
    const int b    = g >> 11;
    const int i    = g & 2047;

    // Q row -> f32 regs (16 elems per lane)
    const unsigned short* qrow = QKV + (size_t)g * 3072;
    float qf[16];
    {
        ushortx8 qa = *reinterpret_cast<const ushortx8*>(qrow + (lane << 4));
        ushortx8 qb = *reinterpret_cast<const ushortx8*>(qrow + (lane << 4) + 8);
#pragma unroll
        for (int t = 0; t < 8; ++t) { qf[t] = bf2f(qa[t]); qf[8 + t] = bf2f(qb[t]); }
    }

    float s[11];
#pragma unroll
    for (int jj = 0; jj < 11; ++jj) {
        const int j = i - 5 + jj;
        const bool valid = ((unsigned)j < 2048u);
        const int jc = min(max(j, 0), 2047);
        const unsigned short* krow = QKV + ((size_t)(b << 11) + jc) * 3072 + 1024;
        ushortx8 ka = *reinterpret_cast<const ushortx8*>(krow + (lane << 4));
        ushortx8 kb = *reinterpret_cast<const ushortx8*>(krow + (lane << 4) + 8);
        float d = 0.f;
#pragma unroll
        for (int t = 0; t < 8; ++t)
            d += qf[t] * bf2f(ka[t]) + qf[8 + t] * bf2f(kb[t]);
#pragma unroll
        for (int off = 32; off >= 1; off >>= 1) d += __shfl_xor(d, off, 64);
        s[jj] = valid ? d * 0.03125f : -1e30f;       // 1/sqrt(1024)
    }

    float mx = s[0];
#pragma unroll
    for (int jj = 1; jj < 11; ++jj) mx = fmaxf(mx, s[jj]);
    float p[11], sum = 0.f;
#pragma unroll
    for (int jj = 0; jj < 11; ++jj) { p[jj] = expf(s[jj] - mx); sum += p[jj]; }
    const float inv = 1.0f / sum;

    if (lane == 0) {
#pragma unroll
        for (int jj = 0; jj < 11; ++jj) psm[w][jj] = p[jj] * inv;
    }
    __syncthreads();

    // full attn row: 8 coalesced f32x4 stores per lane (zeros + band)
    const int lo = i - 5;
    float* arow = attn + (size_t)g * 2048;
#pragma unroll
    for (int e = 0; e < 8; ++e) {
        const int c0 = (e << 8) + (lane << 2);
        f32x4 v = (f32x4){0.f, 0.f, 0.f, 0.f};
        if (c0 + 3 >= lo && c0 <= lo + 10) {
#pragma unroll
            for (int t = 0; t < 4; ++t) {
                const int d = c0 + t - lo;
                if ((unsigned)d < 11u) v[t] = psm[w][d];
            }
        }
        *reinterpret_cast<f32x4*>(arow + c0) = v;
    }

    // context = sum_j p_j * V[j]  (16 cols per lane)
    float cacc[16];
#pragma unroll
    for (int t = 0; t < 16; ++t) cacc[t] = 0.f;
#pragma unroll
    for (int jj = 0; jj < 11; ++jj) {
        const int j  = i - 5 + jj;
        const int jc = min(max(j, 0), 2047);
        const float pj = p[jj] * inv;                // 0 for invalid j
        const unsigned short* vrow = QKV + ((size_t)(b << 11) + jc) * 3072 + 2048;
        ushortx8 va = *reinterpret_cast<const ushortx8*>(vrow + (lane << 4));
        ushortx8 vb = *reinterpret_cast<const ushortx8*>(vrow + (lane << 4) + 8);
#pragma unroll
        for (int t = 0; t < 8; ++t) {
            cacc[t]     += pj * bf2f(va[t]);
            cacc[8 + t] += pj * bf2f(vb[t]);
        }
    }
    unsigned short* cp = ctx + (size_t)g * 1024 + (lane << 4);
    ushortx8 oa, ob;
#pragma unroll
    for (int t = 0; t < 8; ++t) { oa[t] = f2bf(cacc[t]); ob[t] = f2bf(cacc[8 + t]); }
    *reinterpret_cast<ushortx8*>(cp)     = oa;
    *reinterpret_cast<ushortx8*>(cp + 8) = ob;
}

// ------------------------------ launch --------------------------------------
extern "C" void kernel_launch(void* const* d_in, const int* in_sizes, int n_in,
                              void* d_out, int out_size, void* d_ws, size_t ws_size,
                              hipStream_t stream) {
    const float* x  = (const float*)d_in[0];
    const float* Wq = (const float*)d_in[1];
    const float* bq = (const float*)d_in[2];
    const float* Wk = (const float*)d_in[3];
    const float* bk = (const float*)d_in[4];
    const float* Wv = (const float*)d_in[5];
    const float* bv = (const float*)d_in[6];
    const float* Wo = (const float*)d_in[7];
    const float* bo = (const float*)d_in[8];

    const size_t MS = 8192, DD = 1024;

    float* out  = (float*)d_out;              // [8192,1024] f32
    float* attn = out + MS * DD;              // [4,2048,2048] f32

    char* ws = (char*)d_ws;
    unsigned short* xh   = (unsigned short*)ws; ws += MS * DD * 2;        // 16.8 MB
    unsigned short* Wcat = (unsigned short*)ws; ws += 3 * DD * DD * 2;    // 6.3 MB
    unsigned short* Woh  = (unsigned short*)ws; ws += DD * DD * 2;        // 2.1 MB
    unsigned short* QKV  = (unsigned short*)ws; ws += MS * 3 * DD * 2;    // 50.3 MB
    unsigned short* ctx  = (unsigned short*)ws; ws += MS * DD * 2;        // 16.8 MB

    // 1) converts (one kernel): x->xh, Wq/Wk/Wv->Wcat, Wo->Woh
    cvt_all<<<dim3(12288), dim3(256), 0, stream>>>(x, Wq, Wk, Wv, Wo, xh, Wcat, Woh);

    // 2) fused QKV projection: [8192,1024] @ [3072,1024]^T -> bf16 [8192,3072]
    gemm_qkv<<<dim3(64, 24), dim3(256), 0, stream>>>(xh, Wcat, bq, bk, bv,
                                                     QKV, 8192, 3072, 1024);

    // 3) band attention: full attn rows -> d_out, ctx bf16 -> ws
    attn_band_kernel<<<dim3(2048), dim3(256), 0, stream>>>(QKV, attn, ctx);

    // 4) output projection: ctx @ Wo^T + bo -> f32 out
    gemm_out<<<dim3(64, 8), dim3(256), 0, stream>>>(ctx, Woh, bo, out, 8192, 1024, 1024);
}